// Round 4
// baseline (425.341 us; speedup 1.0000x reference)
//
#include <hip/hip_runtime.h>

#define TT 1024
#define NB 4096
#define HH 50
#define DTC 0.1f
#define NL2E2 -2.8853900817779268f      // -2*log2(e)
#define INVNL2E2 -0.34657359027997264f  // 1/NL2E2 = -ln2/2

typedef __attribute__((ext_vector_type(8))) short short8;
typedef __attribute__((ext_vector_type(4))) float float4v;
typedef __attribute__((ext_vector_type(2))) unsigned int uint2v;

__device__ __forceinline__ unsigned short f2bf(float f) {
    unsigned int u = __builtin_bit_cast(unsigned int, f);
    u += 0x7FFFu + ((u >> 16) & 1u);   // RNE
    return (unsigned short)(u >> 16);
}

// ---------------------------------------------------------------------------
// 4-wave structure (round-0), conflict-free reader-keyed exchange (round-2).
// Physical slots p = 0..63, identity logical map: 0..49 state rows, 50 = out
// accumulator row (B slot 50 = const 1), 51 = x slot (B slot 51 = x_t),
// 52..63 dead (A columns/rows zero).
// Wave w owns rows 16w + 4q + r (lane n=lane&15, q=lane>>4, regs r=0..3).
// MFMA slot map, applied identically to A and B (cancellation HW-verified r2):
//   sigma(q, j, f) = 32f + 16*(j>>2) + 4q + (j&3)
// B storage is READER-KEYED: xbuf[buf][f][reader_lane][8 shorts].  Writer lane
// l of wave w packs its 4 rows (slots 16w+4q+r = 32(w>>1)+16(w&1)+4q+r) and
// writes 8B to xbuf[buf][w>>1][l][(w&1)*4] -- lane-linear stride 16 (b64 write
// = free 2-way, b128 read = canonical conflict-free; r2 measured 0 conflicts).
// ---------------------------------------------------------------------------
__global__ void setup_kernel(const float* __restrict__ Jin,
                             const float* __restrict__ Jrec,
                             const float* __restrict__ Jout,
                             const float* __restrict__ bias,
                             const float* __restrict__ h0,
                             float* __restrict__ out0,
                             unsigned short* __restrict__ Aperm) {
    const int tid = threadIdx.x;
    const int blk = blockIdx.x;
    if (blk < 16) {
        const int col = blk * 256 + tid;
        float s = 0.f;
        for (int i = 0; i < HH; ++i) s += Jout[i] * h0[i * NB + col];
        out0[col] = s;
    } else {
        // Aperm layout: [w][f][lane][j] : idx = (w<<10)|(f<<9)|(lane<<3)|j
        for (int idx = tid; idx < 4096; idx += 256) {
            const int j    = idx & 7;
            const int lane = (idx >> 3) & 63;
            const int f    = (idx >> 9) & 1;
            const int w    = (idx >> 10) & 3;
            const int n = lane & 15, q = lane >> 4;
            const int row = 16 * w + n;
            const int k   = 32 * f + 16 * (j >> 2) + 4 * q + (j & 3);
            float v = 0.f;
            if (row < HH) {
                if (k < HH)           v = 2.0f * DTC * Jrec[row * HH + k];
                else if (k == HH)     v = DTC * bias[row];
                else if (k == HH + 1) v = DTC * Jin[row];
            } else if (row == HH) {
                if (k < HH) {
                    float s = 0.f;
                    for (int i = 0; i < HH; ++i) s += Jout[i] * Jrec[i * HH + k];
                    v = 2.0f * DTC * s;
                } else if (k == HH) {
                    float s = 0.f;
                    for (int i = 0; i < HH; ++i) s += Jout[i] * bias[i];
                    v = DTC * s;
                } else if (k == HH + 1) {
                    float s = 0.f;
                    for (int i = 0; i < HH; ++i) s += Jout[i] * Jin[i];
                    v = DTC * s;
                }
            }
            // rows 51..63: zero (x state never fed back; dead rows stay dead)
            Aperm[idx] = f2bf(NL2E2 * v);
        }
    }
}

// Order LDS only; leave global loads/stores in flight (no vmcnt drain).
#define BAR() __asm__ volatile("s_waitcnt lgkmcnt(0)\n\ts_barrier" ::: "memory")

// pack two f32 -> one dword of 2 bf16 (RNE), low short = s0
__device__ __forceinline__ unsigned int cvtpk(float s0, float s1) {
    unsigned int r;
    __asm__("v_cvt_pk_bf16_f32 %0, %1, %2" : "=v"(r) : "v"(s0), "v"(s1));
    return r;
}

// 256 blocks x 256 threads (4 waves).  Block = 16 batch cols; wave w = rows
// 16w..16w+15.  Per step: 2 chained MFMA, <=4 sigmoid pairs, 8B ds_write,
// 2x16B conflict-free ds_read, one barrier.
__global__ void __launch_bounds__(256) rnn_kernel(
        const float* __restrict__ x,
        const float* __restrict__ h0,
        const float* __restrict__ out0,
        const unsigned short* __restrict__ Aperm,
        float* __restrict__ out) {
    __shared__ __align__(16) unsigned short xbuf[2][2][64][8];   // 4 KB

    const int tid  = threadIdx.x;
    const int w    = tid >> 6;
    const int lane = tid & 63;
    const int n    = lane & 15;
    const int q    = lane >> 4;
    const int col  = (blockIdx.x << 4) + n;

    // A fragments (pre-permuted with sigma); 2 coalesced 16B loads per lane
    const short8 a0 = *(const short8*)(Aperm + ((w << 10) | (lane << 3)));
    const short8 a1 = *(const short8*)(Aperm + ((w << 10) | (1 << 9) | (lane << 3)));

    // state hs = NL2E2 * h; reg r = row 16w + 4q + r of column col
    float hs[4];
#pragma unroll
    for (int r = 0; r < 4; ++r) {
        const int row = (w << 4) + (q << 2) + r;
        hs[r] = (row < HH) ? NL2E2 * h0[row * NB + col] : 0.f;
    }
    const bool sp = (w == 3) && (q == 0);   // lanes holding rows 48,49,out(50),x(51)
    if (sp) hs[2] = NL2E2 * out0[col];      // row 50 = Jout @ h0, pre-scaled

    const float* xp = x + col;
    float* outp = out + col;

    // x prefetch chain, depth 3 (sp lanes only)
    float xw = 0.f, xn1 = 0.f, xn2 = 0.f;
    if (sp) { xw = xp[0]; xn1 = xp[NB]; xn2 = xp[2 * NB]; }

    // write slot: 8B at xbuf[buf][w>>1][lane][(w&1)*4]
    unsigned short* wr0 = &xbuf[0][w >> 1][lane][(w & 1) << 2];
    unsigned short* wr1 = &xbuf[1][w >> 1][lane][(w & 1) << 2];

    {   // prologue: sigma(h0) -> buffer 0
        uint2v pk;
        if (w != 3) {
            float s0 = __builtin_amdgcn_rcpf(1.0f + __builtin_amdgcn_exp2f(hs[0]));
            float s1 = __builtin_amdgcn_rcpf(1.0f + __builtin_amdgcn_exp2f(hs[1]));
            float s2 = __builtin_amdgcn_rcpf(1.0f + __builtin_amdgcn_exp2f(hs[2]));
            float s3 = __builtin_amdgcn_rcpf(1.0f + __builtin_amdgcn_exp2f(hs[3]));
            pk[0] = cvtpk(s0, s1);
            pk[1] = cvtpk(s2, s3);
        } else {
            float s0 = __builtin_amdgcn_rcpf(1.0f + __builtin_amdgcn_exp2f(hs[0]));
            float s1 = __builtin_amdgcn_rcpf(1.0f + __builtin_amdgcn_exp2f(hs[1]));
            pk[0] = cvtpk(s0, s1);
            pk[1] = cvtpk(sp ? 1.0f : 0.f, xw);   // slot50 = 1, slot51 = x_0
        }
        *(uint2v*)wr0 = pk;
    }
    BAR();

#pragma unroll 2
    for (int t = 0; t < TT; ++t) {
        const int buf = t & 1;
        // conflict-free b128 reads: lane-linear stride 16
        short8 b0 = *(const short8*)&xbuf[buf][0][lane][0];
        short8 b1 = *(const short8*)&xbuf[buf][1][lane][0];

        // prefetch x_{t+3}
        float xf = 0.f;
        if (sp) {
            int tt = (t + 3 < TT) ? t + 3 : TT - 1;
            xf = xp[tt * NB];
        }

        float4v acc = {0.f, 0.f, 0.f, 0.f};
        acc = __builtin_amdgcn_mfma_f32_16x16x32_bf16(a0, b0, acc, 0, 0, 0);
        acc = __builtin_amdgcn_mfma_f32_16x16x32_bf16(a1, b1, acc, 0, 0, 0);

#pragma unroll
        for (int r = 0; r < 4; ++r)
            hs[r] = __builtin_fmaf(hs[r], 1.0f - DTC, acc[r]);

        // r' = sigmoid(2h) = rcp(1 + exp2(hs)); pack to bf16 via cvt_pk (RNE)
        uint2v pk;
        if (w != 3) {
            float s0 = __builtin_amdgcn_rcpf(1.0f + __builtin_amdgcn_exp2f(hs[0]));
            float s1 = __builtin_amdgcn_rcpf(1.0f + __builtin_amdgcn_exp2f(hs[1]));
            float s2 = __builtin_amdgcn_rcpf(1.0f + __builtin_amdgcn_exp2f(hs[2]));
            float s3 = __builtin_amdgcn_rcpf(1.0f + __builtin_amdgcn_exp2f(hs[3]));
            pk[0] = cvtpk(s0, s1);
            pk[1] = cvtpk(s2, s3);
        } else {
            float s0 = __builtin_amdgcn_rcpf(1.0f + __builtin_amdgcn_exp2f(hs[0]));
            float s1 = __builtin_amdgcn_rcpf(1.0f + __builtin_amdgcn_exp2f(hs[1]));
            pk[0] = cvtpk(s0, s1);
            pk[1] = cvtpk(sp ? 1.0f : 0.f, xn1);   // slot50 = 1, slot51 = x_{t+1}
        }
        *(uint2v*)(buf ? wr0 : wr1) = pk;

        if (sp) outp[t * NB] = hs[2] * INVNL2E2;   // out_t, off the barrier path

        xn1 = xn2; xn2 = xf;
        BAR();
    }
}

extern "C" void kernel_launch(void* const* d_in, const int* in_sizes, int n_in,
                              void* d_out, int out_size, void* d_ws, size_t ws_size,
                              hipStream_t stream) {
    (void)in_sizes; (void)n_in; (void)out_size; (void)ws_size;
    const float* x    = (const float*)d_in[0];
    const float* Jin  = (const float*)d_in[1];
    const float* Jrec = (const float*)d_in[2];
    const float* Jout = (const float*)d_in[3];
    const float* bias = (const float*)d_in[4];
    const float* h0   = (const float*)d_in[5];
    float* out = (float*)d_out;

    float* ws_out0 = (float*)d_ws;                            // 4096 f32
    unsigned short* ws_A = (unsigned short*)(ws_out0 + NB);   // 4096 bf16 (permuted)

    hipLaunchKernelGGL(setup_kernel, dim3(17), dim3(256), 0, stream,
                       Jin, Jrec, Jout, bias, h0, ws_out0, ws_A);
    hipLaunchKernelGGL(rnn_kernel, dim3(NB / 16), dim3(256), 0, stream,
                       x, h0, ws_out0, ws_A, out);
}

// Round 5
// 333.662 us; speedup vs baseline: 1.2748x; 1.2748x over previous
//
#include <hip/hip_runtime.h>

#define TT 1024
#define NB 4096
#define HH 50
#define DTC 0.1f
#define NL2E2 -2.8853900817779268f   // -2*log2(e)

typedef __attribute__((ext_vector_type(8))) short short8;
typedef __attribute__((ext_vector_type(4))) float float4v;
typedef __attribute__((ext_vector_type(2))) unsigned int uint2v;

__device__ __forceinline__ unsigned short f2bf(float f) {
    unsigned int u = __builtin_bit_cast(unsigned int, f);
    u += 0x7FFFu + ((u >> 16) & 1u);   // RNE
    return (unsigned short)(u >> 16);
}

// Raw barrier: order LDS only; leave global loads/stores in flight (no vmcnt drain).
#define BAR() __asm__ volatile("s_waitcnt lgkmcnt(0)\n\ts_barrier" ::: "memory")

// A_aug 64x64 bf16, dt and the sigmoid 1/2 folded in:
//   rows 0..49:  [0.2*Jrec | 0.1*bias | 0.1*Jin | 0]
//   row  50:     [0.2*Jout@Jrec | 0.1*Jout@bias | 0.1*Jout@Jin | 0]   (out recurrence)
// B-slots per step: rows 0..49 = sigmoid(2h)=(1+tanh h)/2, row 50 = 1, row 51 = x_t.
// Then h_next = 0.9*h + A_aug @ r'  reproduces the reference exactly.
__global__ void setup_kernel(const float* __restrict__ Jin,
                             const float* __restrict__ Jrec,
                             const float* __restrict__ Jout,
                             const float* __restrict__ bias,
                             const float* __restrict__ h0,
                             float* __restrict__ out0,
                             unsigned short* __restrict__ Aaug) {
    const int tid = threadIdx.x;
    const int blk = blockIdx.x;
    if (blk < 16) {
        const int col = blk * 256 + tid;
        float s = 0.f;
        for (int i = 0; i < HH; ++i) s += Jout[i] * h0[i * NB + col];
        out0[col] = s;
    } else {
        for (int idx = tid; idx < 64 * 64; idx += 256) {
            const int row = idx >> 6, k = idx & 63;
            float v = 0.f;
            if (row < HH) {
                if (k < HH)           v = 2.0f * DTC * Jrec[row * HH + k];
                else if (k == HH)     v = DTC * bias[row];
                else if (k == HH + 1) v = DTC * Jin[row];
            } else if (row == HH) {
                if (k < HH) {
                    float s = 0.f;
                    for (int i = 0; i < HH; ++i) s += Jout[i] * Jrec[i * HH + k];
                    v = 2.0f * DTC * s;
                } else if (k == HH) {
                    float s = 0.f;
                    for (int i = 0; i < HH; ++i) s += Jout[i] * bias[i];
                    v = DTC * s;
                } else if (k == HH + 1) {
                    float s = 0.f;
                    for (int i = 0; i < HH; ++i) s += Jout[i] * Jin[i];
                    v = DTC * s;
                }
            }
            Aaug[idx] = f2bf(v);
        }
    }
}

// 256 blocks x 256 threads; wave w = M-tile rows 16w..16w+15, block = 16 batch cols.
// h in fp32 C-layout regs (row = 16w+4q+reg, col = lane&15). Row 50 carries out_t.
// vs round-0: the two MFMAs are DE-CHAINED (independent accumulators) and the
// 0.9*h scale is computed in the LDS-read shadow -- removes one MFMA latency
// from the loop-carried serial chain.
__global__ void __launch_bounds__(256) rnn_kernel(
        const float* __restrict__ x,
        const float* __restrict__ h0,
        const float* __restrict__ out0,
        const unsigned short* __restrict__ Aaug,
        float* __restrict__ out) {
    __shared__ unsigned short rbuf[2][16][72];

    const int tid  = threadIdx.x;
    const int w    = tid >> 6;
    const int lane = tid & 63;
    const int n    = lane & 15;
    const int q    = lane >> 4;
    const int col  = (blockIdx.x << 4) + n;
    const int row0 = 16 * w + 4 * q;

    // A fragments, contiguous our-k (slot permutation cancels between A and B frags)
    short8 a0, a1;
    {
        const unsigned short* ap = Aaug + ((16 * w + n) << 6) + (q << 3);
        a0 = *(const short8*)ap;
        a1 = *(const short8*)(ap + 32);
    }

    float h[4];
#pragma unroll
    for (int r = 0; r < 4; ++r)
        h[r] = (row0 + r < HH) ? h0[(row0 + r) * NB + col] : 0.f;
    const bool outlane = (w == 3) && (q == 0);   // regs: 48,49,out(50),x-slot(51)
    if (outlane) h[2] = out0[col];

    const float* xp = x + col;
    float* outp = out + col;

    // x prefetch chain, depth 3 (covers HBM cold-miss latency ~900cy)
    float xw = 0.f, xn1 = 0.f, xn2 = 0.f;
    if (outlane) { xw = xp[0]; xn1 = xp[NB]; xn2 = xp[2 * NB]; }

    // initial r'(h0) into buffer 0
    {
        unsigned int u[4];
#pragma unroll
        for (int r = 0; r < 4; ++r) {
            float e = __builtin_amdgcn_exp2f(NL2E2 * h[r]);
            float rv = __builtin_amdgcn_rcpf(1.0f + e);
            u[r] = __builtin_bit_cast(unsigned int, rv);
        }
        if (outlane) { u[2] = 0x3F800000u; u[3] = __builtin_bit_cast(unsigned int, xw); }
#pragma unroll
        for (int r = 0; r < 4; ++r) u[r] += 0x8000u;
        uint2v pk;
        pk[0] = __builtin_amdgcn_perm(u[1], u[0], 0x07060302u);
        pk[1] = __builtin_amdgcn_perm(u[3], u[2], 0x07060302u);
        *(uint2v*)&rbuf[0][n][row0] = pk;
    }

    unsigned short* wr[2] = { &rbuf[0][n][row0], &rbuf[1][n][row0] };
    const unsigned short* rd[2] = { &rbuf[0][n][q << 3], &rbuf[1][n][q << 3] };

    __syncthreads();   // one-time full sync (drains prefetches once; fine)

#pragma unroll 2
    for (int t = 0; t < TT; ++t) {
        const int buf = t & 1;
        short8 b0 = *(const short8*)(rd[buf]);
        short8 b1 = *(const short8*)(rd[buf] + 32);

        // 0.9*h depends only on old state: issue in the ds_read shadow
        float pre[4];
#pragma unroll
        for (int r = 0; r < 4; ++r) pre[r] = h[r] * (1.0f - DTC);

        // prefetch x_{t+3}
        float xf = 0.f;
        if (outlane) {
            int tt = (t + 3 < TT) ? t + 3 : TT - 1;
            xf = xp[tt * NB];
        }

        // de-chained MFMAs: independent accumulators, summed after
        float4v acc0 = {0.f, 0.f, 0.f, 0.f};
        float4v acc1 = {0.f, 0.f, 0.f, 0.f};
        acc0 = __builtin_amdgcn_mfma_f32_16x16x32_bf16(a0, b0, acc0, 0, 0, 0);
        acc1 = __builtin_amdgcn_mfma_f32_16x16x32_bf16(a1, b1, acc1, 0, 0, 0);

#pragma unroll
        for (int r = 0; r < 4; ++r)
            h[r] = (pre[r] + acc0[r]) + acc1[r];

        // r' = sigmoid(2h); special slots: row50=1, row51=x_{t+1}
        unsigned int u[4];
#pragma unroll
        for (int r = 0; r < 4; ++r) {
            float e = __builtin_amdgcn_exp2f(NL2E2 * h[r]);
            float rv = __builtin_amdgcn_rcpf(1.0f + e);
            u[r] = __builtin_bit_cast(unsigned int, rv);
        }
        if (outlane) { u[2] = 0x3F800000u; u[3] = __builtin_bit_cast(unsigned int, xn1); }
#pragma unroll
        for (int r = 0; r < 4; ++r) u[r] += 0x8000u;   // round-half-up to bf16
        uint2v pk;
        pk[0] = __builtin_amdgcn_perm(u[1], u[0], 0x07060302u);
        pk[1] = __builtin_amdgcn_perm(u[3], u[2], 0x07060302u);
        *(uint2v*)wr[buf ^ 1] = pk;

        if (outlane) outp[t * NB] = h[2];   // out_t, off the barrier path

        xn1 = xn2; xn2 = xf;
        BAR();
    }
}

extern "C" void kernel_launch(void* const* d_in, const int* in_sizes, int n_in,
                              void* d_out, int out_size, void* d_ws, size_t ws_size,
                              hipStream_t stream) {
    (void)in_sizes; (void)n_in; (void)out_size; (void)ws_size;
    const float* x    = (const float*)d_in[0];
    const float* Jin  = (const float*)d_in[1];
    const float* Jrec = (const float*)d_in[2];
    const float* Jout = (const float*)d_in[3];
    const float* bias = (const float*)d_in[4];
    const float* h0   = (const float*)d_in[5];
    float* out = (float*)d_out;

    float* ws_out0 = (float*)d_ws;                            // 4096 f32
    unsigned short* ws_A = (unsigned short*)(ws_out0 + NB);   // 4096 bf16, 16B aligned

    hipLaunchKernelGGL(setup_kernel, dim3(17), dim3(256), 0, stream,
                       Jin, Jrec, Jout, bias, h0, ws_out0, ws_A);
    hipLaunchKernelGGL(rnn_kernel, dim3(256), dim3(256), 0, stream,
                       x, h0, ws_out0, ws_A, out);
}